// Round 6
// baseline (171.947 us; speedup 1.0000x reference)
//
#include <hip/hip_runtime.h>

// e = exp(-((x-cx)^2 w0^2 + ...)) with w' = w*sqrt(log2 e):
//   t_k = fma(x_k, w'_k, -c_k w'_k);  e = exp2(-(t0^2+t1^2+t2^2))
// du_k = -2 x1_k w_k^2 h e = t_k * (NEG_2LN2 * h * w'_k) * e
//
// R5: spatial binning (4^3 cells) + per-cell conservative center prefilter.
// Most pairs have e==0 (w' up to 60 => tiny ellipsoids). Survivor fraction
// ~0.33. Prefilter box is the FIXED cell box => output deterministic even
// though scatter uses atomics (survivor set independent of intra-cell order).
typedef float v2f __attribute__((ext_vector_type(2)));

static constexpr float SQRT_LOG2E = 1.2011224087864498f;   // sqrt(log2(e))
static constexpr float NEG_2LN2   = -1.3862943611198906f;  // -2*ln(2)
static constexpr float S2_CUT     = 30.0f;                 // drop if s2 >= 30
#define NCELL 64                                           // 4x4x4

__device__ __forceinline__ v2f sp(float s) { return (v2f){s, s}; }
__device__ __forceinline__ v2f vfma(v2f a, v2f b, v2f c) {
    return __builtin_elementwise_fma(a, b, c);
}

// ------------------------- sort pipeline -------------------------
__device__ __forceinline__ int cell_of(float a, float b, float c) {
    int cx = (int)(a * 4.f); cx = cx < 0 ? 0 : (cx > 3 ? 3 : cx);
    int cy = (int)(b * 4.f); cy = cy < 0 ? 0 : (cy > 3 ? 3 : cy);
    int cz = (int)(c * 4.f); cz = cz < 0 ? 0 : (cz > 3 ? 3 : cz);
    return cx + 4 * cy + 16 * cz;
}

__global__ void zero_hist(int* hist) {
    if (threadIdx.x < NCELL) hist[threadIdx.x] = 0;
}

__global__ void hist_kernel(const float* __restrict__ x, int* __restrict__ hist, int N) {
    int i = blockIdx.x * 256 + threadIdx.x;
    if (i < N) atomicAdd(&hist[cell_of(x[3 * i], x[3 * i + 1], x[3 * i + 2])], 1);
}

__global__ void scan_kernel(const int* __restrict__ hist, int* __restrict__ offs,
                            int* __restrict__ cursor) {
    int tid = threadIdx.x;          // 64 threads = 1 wave
    int v = hist[tid];
    int incl = v;
    for (int o = 1; o < 64; o <<= 1) {
        int t = __shfl_up(incl, o);
        if (tid >= o) incl += t;
    }
    offs[tid + 1] = incl;
    if (tid == 0) offs[0] = 0;
    cursor[tid] = incl - v;         // exclusive prefix
}

__global__ void scatter_kernel(const float* __restrict__ x, int* __restrict__ cursor,
                               int* __restrict__ perm, float* __restrict__ xs,
                               float* __restrict__ ys, float* __restrict__ zs, int N) {
    int i = blockIdx.x * 256 + threadIdx.x;
    if (i < N) {
        float a = x[3 * i], b = x[3 * i + 1], c = x[3 * i + 2];
        int pos = atomicAdd(&cursor[cell_of(a, b, c)], 1);
        perm[pos] = i; xs[pos] = a; ys[pos] = b; zs[pos] = c;
    }
}

// ------------------------- main sorted kernel -------------------------
template <int SET>  // 0: ux,uy,uz   1: P,Px   2: Q,Qy   3: R,Rz
__device__ __forceinline__ void srbf_cell_body(
    const float* __restrict__ xs, const float* __restrict__ ys,
    const float* __restrict__ zs,
    const float* __restrict__ h, const float* __restrict__ c,
    const float* __restrict__ w,
    const int* __restrict__ offs, const int* __restrict__ perm,
    float* __restrict__ dst, int N, int jbase, int jcount, int direct,
    float4* lds4)
{
    constexpr int OB = (SET == 0) ? 0 : (2 * SET + 1);
    const int tid = threadIdx.x, lane = tid & 63, wv = tid >> 6;  // 128 thr = 2 waves
    float* ldsb2 = (float*)(lds4 + 2 * jcount);

    // stage per-center constants
    for (int jj = tid; jj < jcount; jj += 128) {
        const int gj = jbase + jj;
        float hj  = h[gj];
        float w0  = w[3 * gj + 0] * SQRT_LOG2E;
        float w1  = w[3 * gj + 1] * SQRT_LOG2E;
        float w2  = w[3 * gj + 2] * SQRT_LOG2E;
        float cw0 = -c[3 * gj + 0] * w0;
        float cw1 = -c[3 * gj + 1] * w1;
        float cw2 = -c[3 * gj + 2] * w2;
        lds4[jj * 2 + 0] = make_float4(w0, w1, w2, cw0);
        if constexpr (SET == 0) {
            lds4[jj * 2 + 1] = make_float4(cw1, cw2, NEG_2LN2 * hj * w0,
                                           NEG_2LN2 * hj * w1);
            ldsb2[jj] = NEG_2LN2 * hj * w2;
        } else {
            constexpr int K = SET - 1;
            float wk = (K == 0) ? w0 : (K == 1 ? w1 : w2);
            lds4[jj * 2 + 1] = make_float4(cw1, cw2, hj, NEG_2LN2 * hj * wk);
        }
    }
    __syncthreads();

    // fixed cell box (prefilter geometry is per-cell => deterministic output)
    const int cellid = blockIdx.x;
    const float mid0 = ((cellid & 3) + 0.5f) * 0.25f;
    const float mid1 = (((cellid >> 2) & 3) + 0.5f) * 0.25f;
    const float mid2 = (((cellid >> 4) & 3) + 0.5f) * 0.25f;
    const float hf = 0.125f;
    const int start = offs[cellid], end = offs[cellid + 1];

    for (int base = start + 256 * wv; base < end; base += 512) {
        int i0 = base + lane;
        int idx[4]; bool val[4];
#pragma unroll
        for (int g4 = 0; g4 < 4; ++g4) {
            int q = i0 + 64 * g4;
            val[g4] = (q < end);
            idx[g4] = val[g4] ? q : (end - 1);
        }
        v2f px[2], py[2], pz[2];
        px[0] = (v2f){xs[idx[0]], xs[idx[1]]};
        py[0] = (v2f){ys[idx[0]], ys[idx[1]]};
        pz[0] = (v2f){zs[idx[0]], zs[idx[1]]};
        px[1] = (v2f){xs[idx[2]], xs[idx[3]]};
        py[1] = (v2f){ys[idx[2]], ys[idx[3]]};
        pz[1] = (v2f){zs[idx[2]], zs[idx[3]]};

        v2f a0[2] = {sp(0.f), sp(0.f)};
        v2f a1[2] = {sp(0.f), sp(0.f)};
        v2f a2[2] = {sp(0.f), sp(0.f)};

        for (int j0 = 0; j0 < jcount; j0 += 64) {
            // prefilter: lane tests center j0+lane against the cell box
            float smin;
            {
                const float4 A = lds4[(j0 + lane) * 2 + 0];
                const float4 B = lds4[(j0 + lane) * 2 + 1];
                float v0 = fmaf(mid0, A.x, A.w);      // (mid-c)*w'
                float v1 = fmaf(mid1, A.y, B.x);
                float v2_ = fmaf(mid2, A.z, B.y);
                float d0 = fmaxf(fabsf(v0) - hf * A.x, 0.f);
                float d1 = fmaxf(fabsf(v1) - hf * A.y, 0.f);
                float d2 = fmaxf(fabsf(v2_) - hf * A.z, 0.f);
                smin = fmaf(d0, d0, fmaf(d1, d1, d2 * d2));
            }
            unsigned long long mask = __ballot(smin < S2_CUT);
            while (mask) {
                int jj = j0 + (__ffsll((unsigned long long)mask) - 1);
                mask &= mask - 1;
                const float4 A = lds4[jj * 2 + 0];   // w0,w1,w2,cw0
                const float4 B = lds4[jj * 2 + 1];   // cw1,cw2,(b0|h),(b1|bk)
                float b2 = 0.f;
                if constexpr (SET == 0) b2 = ldsb2[jj];
#pragma unroll
                for (int g = 0; g < 2; ++g) {
                    v2f t0 = vfma(px[g], sp(A.x), sp(A.w));
                    v2f t1 = vfma(py[g], sp(A.y), sp(B.x));
                    v2f t2 = vfma(pz[g], sp(A.z), sp(B.y));
                    v2f s  = vfma(t0, t0, vfma(t1, t1, t2 * t2));
                    v2f e  = (v2f){__builtin_amdgcn_exp2f(-s.x),
                                   __builtin_amdgcn_exp2f(-s.y)};
                    if constexpr (SET == 0) {
                        a0[g] = vfma(t0, sp(B.z) * e, a0[g]);
                        a1[g] = vfma(t1, sp(B.w) * e, a1[g]);
                        a2[g] = vfma(t2, sp(b2)  * e, a2[g]);
                    } else {
                        constexpr int K = SET - 1;
                        v2f tk = (K == 0) ? t0 : (K == 1 ? t1 : t2);
                        a0[g] = vfma(sp(B.z), e, a0[g]);
                        a1[g] = vfma(tk, sp(B.w) * e, a1[g]);
                    }
                }
            }
        }

        float r0[4] = {a0[0].x, a0[0].y, a0[1].x, a0[1].y};
        float r1[4] = {a1[0].x, a1[0].y, a1[1].x, a1[1].y};
        float r2[4] = {a2[0].x, a2[0].y, a2[1].x, a2[1].y};
#pragma unroll
        for (int g4 = 0; g4 < 4; ++g4) {
            if (!val[g4]) continue;
            int pos = i0 + 64 * g4;
            int tgt = direct ? perm[pos] : pos;
            dst[(OB + 0) * N + tgt] = r0[g4];
            dst[(OB + 1) * N + tgt] = r1[g4];
            if constexpr (SET == 0) dst[2 * N + tgt] = r2[g4];
        }
    }
}

__global__ __launch_bounds__(128, 8) void srbf_sorted(
    const float* xs, const float* ys, const float* zs,
    const float* h1, const float* c1, const float* w1,
    const float* h2, const float* c2, const float* w2,
    const float* h3, const float* c3, const float* w3,
    const float* h4, const float* c4, const float* w4,
    const int* offs, const int* perm,
    float* out, float* ws, int N, int jcount, int split)
{
    extern __shared__ float4 lds4[];
    const int jbase = blockIdx.y * jcount;
    const int direct = (split == 1);
    float* dst = direct ? out : (ws + (size_t)blockIdx.y * 9 * N);
    switch (blockIdx.z) {
    case 0: srbf_cell_body<0>(xs, ys, zs, h1, c1, w1, offs, perm, dst, N, jbase, jcount, direct, lds4); break;
    case 1: srbf_cell_body<1>(xs, ys, zs, h2, c2, w2, offs, perm, dst, N, jbase, jcount, direct, lds4); break;
    case 2: srbf_cell_body<2>(xs, ys, zs, h3, c3, w3, offs, perm, dst, N, jbase, jcount, direct, lds4); break;
    case 3: srbf_cell_body<3>(xs, ys, zs, h4, c4, w4, offs, perm, dst, N, jbase, jcount, direct, lds4); break;
    }
}

__global__ __launch_bounds__(256) void reduce_scatter(
    const float* __restrict__ ws, const int* __restrict__ perm,
    float* __restrict__ out, int N, int split)
{
    int pos = blockIdx.x * 256 + threadIdx.x;
    if (pos < N) {
        int op = perm[pos];
#pragma unroll
        for (int row = 0; row < 9; ++row) {
            float acc = 0.f;
            for (int p = 0; p < split; ++p)
                acc += ws[((size_t)p * 9 + row) * N + pos];
            out[row * N + op] = acc;
        }
    }
}

// ------------------------- R4 fallback (unsorted) -------------------------
template <int SET>
__device__ __forceinline__ void srbf_body_fb(
    const float* __restrict__ x, const float* __restrict__ h,
    const float* __restrict__ c, const float* __restrict__ w,
    float* __restrict__ dst, int N, int jbase, int jcount, float4* lds4)
{
    constexpr int OB = (SET == 0) ? 0 : (2 * SET + 1);
    const int tid = threadIdx.x;
    float* ldsb2 = (float*)(lds4 + 2 * jcount);
    for (int jj = tid; jj < jcount; jj += 256) {
        const int gj = jbase + jj;
        float hj  = h[gj];
        float w0  = w[3 * gj + 0] * SQRT_LOG2E;
        float w1  = w[3 * gj + 1] * SQRT_LOG2E;
        float w2  = w[3 * gj + 2] * SQRT_LOG2E;
        float cw0 = -c[3 * gj + 0] * w0;
        float cw1 = -c[3 * gj + 1] * w1;
        float cw2 = -c[3 * gj + 2] * w2;
        lds4[jj * 2 + 0] = make_float4(w0, w1, w2, cw0);
        if constexpr (SET == 0) {
            lds4[jj * 2 + 1] = make_float4(cw1, cw2, NEG_2LN2 * hj * w0, NEG_2LN2 * hj * w1);
            ldsb2[jj] = NEG_2LN2 * hj * w2;
        } else {
            constexpr int K = SET - 1;
            float wk = (K == 0) ? w0 : (K == 1 ? w1 : w2);
            lds4[jj * 2 + 1] = make_float4(cw1, cw2, hj, NEG_2LN2 * hj * wk);
        }
    }
    __syncthreads();
    const int i0 = blockIdx.x * 1024 + tid;
    v2f px[2], py[2], pz[2];
#pragma unroll
    for (int g = 0; g < 2; ++g) {
        const int ia = i0 + 512 * g, ib = ia + 256;
        px[g] = (v2f){x[3 * ia + 0], x[3 * ib + 0]};
        py[g] = (v2f){x[3 * ia + 1], x[3 * ib + 1]};
        pz[g] = (v2f){x[3 * ia + 2], x[3 * ib + 2]};
    }
    v2f a0[2] = {sp(0.f), sp(0.f)}, a1[2] = {sp(0.f), sp(0.f)}, a2[2] = {sp(0.f), sp(0.f)};
#pragma unroll 2
    for (int jj = 0; jj < jcount; ++jj) {
        const float4 A = lds4[jj * 2 + 0];
        const float4 B = lds4[jj * 2 + 1];
        float b2 = 0.f;
        if constexpr (SET == 0) b2 = ldsb2[jj];
#pragma unroll
        for (int g = 0; g < 2; ++g) {
            v2f t0 = vfma(px[g], sp(A.x), sp(A.w));
            v2f t1 = vfma(py[g], sp(A.y), sp(B.x));
            v2f t2 = vfma(pz[g], sp(A.z), sp(B.y));
            v2f s  = vfma(t0, t0, vfma(t1, t1, t2 * t2));
            v2f e  = (v2f){__builtin_amdgcn_exp2f(-s.x), __builtin_amdgcn_exp2f(-s.y)};
            if constexpr (SET == 0) {
                a0[g] = vfma(t0, sp(B.z) * e, a0[g]);
                a1[g] = vfma(t1, sp(B.w) * e, a1[g]);
                a2[g] = vfma(t2, sp(b2)  * e, a2[g]);
            } else {
                constexpr int K = SET - 1;
                v2f tk = (K == 0) ? t0 : (K == 1 ? t1 : t2);
                a0[g] = vfma(sp(B.z), e, a0[g]);
                a1[g] = vfma(tk, sp(B.w) * e, a1[g]);
            }
        }
    }
#pragma unroll
    for (int g = 0; g < 2; ++g) {
        const int ia = i0 + 512 * g, ib = ia + 256;
        dst[(OB + 0) * N + ia] = a0[g].x;  dst[(OB + 0) * N + ib] = a0[g].y;
        dst[(OB + 1) * N + ia] = a1[g].x;  dst[(OB + 1) * N + ib] = a1[g].y;
        if constexpr (SET == 0) { dst[2 * N + ia] = a2[g].x; dst[2 * N + ib] = a2[g].y; }
    }
}

__global__ __launch_bounds__(256, 8) void srbf_fallback(
    const float* x,
    const float* h1, const float* c1, const float* w1,
    const float* h2, const float* c2, const float* w2,
    const float* h3, const float* c3, const float* w3,
    const float* h4, const float* c4, const float* w4,
    float* out, float* ws, int N, int jcount, int split)
{
    extern __shared__ float4 lds4[];
    const int jbase = blockIdx.y * jcount;
    float* dst = (split > 1) ? (ws + (size_t)blockIdx.y * 9 * N) : out;
    switch (blockIdx.z) {
    case 0: srbf_body_fb<0>(x, h1, c1, w1, dst, N, jbase, jcount, lds4); break;
    case 1: srbf_body_fb<1>(x, h2, c2, w2, dst, N, jbase, jcount, lds4); break;
    case 2: srbf_body_fb<2>(x, h3, c3, w3, dst, N, jbase, jcount, lds4); break;
    case 3: srbf_body_fb<3>(x, h4, c4, w4, dst, N, jbase, jcount, lds4); break;
    }
}

__global__ __launch_bounds__(256) void reduce_fb(
    const float4* __restrict__ ws, float4* __restrict__ out, int total4, int split)
{
    const int i = blockIdx.x * 256 + threadIdx.x;
    if (i < total4) {
        float4 acc = ws[i];
#pragma unroll 16
        for (int p = 1; p < split; ++p) {
            const float4 v = ws[(size_t)p * total4 + i];
            acc.x += v.x; acc.y += v.y; acc.z += v.z; acc.w += v.w;
        }
        out[i] = acc;
    }
}

// ------------------------- launch -------------------------
extern "C" void kernel_launch(void* const* d_in, const int* in_sizes, int n_in,
                              void* d_out, int out_size, void* d_ws, size_t ws_size,
                              hipStream_t stream)
{
    const float* x = (const float*)d_in[0];
    const int N  = in_sizes[0] / 3;   // 32768
    const int N1 = in_sizes[1];       // 1024
    float* out = (float*)d_out;
    float* wsf = (float*)d_ws;

    // ws layout (floats): partials split*9N | xs N | ys N | zs N | perm N | hist 64 | offs 65 | cursor 64
    int split = 0;
    {
        const int cand[5] = {16, 8, 4, 2, 1};
        for (int ci = 0; ci < 5; ++ci) {
            int s = cand[ci];
            if ((N1 % s) == 0 &&
                ws_size >= ((size_t)s * 9 * N + 4 * (size_t)N + 256) * 4) {
                split = s; break;
            }
        }
    }

    if (split) {
        size_t off = (size_t)split * 9 * N;
        float* xs = wsf + off;
        float* ys = xs + N;
        float* zs = ys + N;
        int* perm   = (int*)(zs + N);
        int* hist   = perm + N;
        int* offs   = hist + 64;
        int* cursor = offs + 65;

        zero_hist<<<1, 64, 0, stream>>>(hist);
        hist_kernel<<<(N + 255) / 256, 256, 0, stream>>>(x, hist, N);
        scan_kernel<<<1, 64, 0, stream>>>(hist, offs, cursor);
        scatter_kernel<<<(N + 255) / 256, 256, 0, stream>>>(x, cursor, perm, xs, ys, zs, N);

        const int jcount = N1 / split;
        dim3 grid(NCELL, split, 4);
        const size_t lds_bytes = (size_t)jcount * (2 * sizeof(float4) + sizeof(float));
        srbf_sorted<<<grid, 128, lds_bytes, stream>>>(
            xs, ys, zs,
            (const float*)d_in[1],  (const float*)d_in[2],  (const float*)d_in[3],
            (const float*)d_in[4],  (const float*)d_in[5],  (const float*)d_in[6],
            (const float*)d_in[7],  (const float*)d_in[8],  (const float*)d_in[9],
            (const float*)d_in[10], (const float*)d_in[11], (const float*)d_in[12],
            offs, perm, out, wsf, N, jcount, split);

        if (split > 1)
            reduce_scatter<<<(N + 255) / 256, 256, 0, stream>>>(wsf, perm, out, N, split);
    } else {
        // unsorted fallback (R4)
        int fsplit = 1;
        for (int s = 16; s >= 2; s >>= 1) {
            if (ws_size >= (size_t)s * 9 * N * sizeof(float) && (N1 % s) == 0) {
                fsplit = s; break;
            }
        }
        const int jcount = N1 / fsplit;
        dim3 grid(N / 1024, fsplit, 4);
        const size_t lds_bytes = (size_t)jcount * (2 * sizeof(float4) + sizeof(float));
        srbf_fallback<<<grid, 256, lds_bytes, stream>>>(
            x,
            (const float*)d_in[1],  (const float*)d_in[2],  (const float*)d_in[3],
            (const float*)d_in[4],  (const float*)d_in[5],  (const float*)d_in[6],
            (const float*)d_in[7],  (const float*)d_in[8],  (const float*)d_in[9],
            (const float*)d_in[10], (const float*)d_in[11], (const float*)d_in[12],
            out, wsf, N, jcount, fsplit);
        if (fsplit > 1) {
            const int total4 = 9 * N / 4;
            reduce_fb<<<(total4 + 255) / 256, 256, 0, stream>>>(
                (const float4*)wsf, (float4*)out, total4, fsplit);
        }
    }
}

// Round 7
// 104.455 us; speedup vs baseline: 1.6461x; 1.6461x over previous
//
#include <hip/hip_runtime.h>

// e = exp(-((x-cx)^2 w0^2 + ...)) with w' = w*sqrt(log2 e):
//   t_k = fma(x_k, w'_k, -c_k w'_k);  e = exp2(-(t0^2+t1^2+t2^2))
// du_k = -2 x1_k w_k^2 h e = t_k * (NEG_2LN2 * h * w'_k) * e
//
// R6: sparse path with (a) fused single-block counting sort (LDS atomics, no
// global-atomic storm), (b) per-block survivor list built ONCE by wave 0 via
// ballot-prefix compaction (deterministic order), (c) split=8 partials.
typedef float v2f __attribute__((ext_vector_type(2)));

static constexpr float SQRT_LOG2E = 1.2011224087864498f;   // sqrt(log2(e))
static constexpr float NEG_2LN2   = -1.3862943611198906f;  // -2*ln(2)
static constexpr float S2_CUT     = 30.0f;                 // drop if smin >= 30 (log2 units)
#define NCELL 64                                           // 4x4x4

__device__ __forceinline__ v2f sp(float s) { return (v2f){s, s}; }
__device__ __forceinline__ v2f vfma(v2f a, v2f b, v2f c) {
    return __builtin_elementwise_fma(a, b, c);
}

__device__ __forceinline__ int cell_of(float a, float b, float c) {
    int cx = (int)(a * 4.f); cx = cx < 0 ? 0 : (cx > 3 ? 3 : cx);
    int cy = (int)(b * 4.f); cy = cy < 0 ? 0 : (cy > 3 ? 3 : cy);
    int cz = (int)(c * 4.f); cz = cz < 0 ? 0 : (cz > 3 ? 3 : cz);
    return cx + 4 * cy + 16 * cz;
}

// ---------------- fused counting sort: ONE block ----------------
__global__ __launch_bounds__(1024) void sort_kernel(
    const float* __restrict__ x, float* __restrict__ xs, float* __restrict__ ys,
    float* __restrict__ zs, int* __restrict__ perm, int* __restrict__ offs, int N)
{
    __shared__ int lh[NCELL];
    __shared__ int lcur[NCELL];
    const int tid = threadIdx.x;
    if (tid < NCELL) lh[tid] = 0;
    __syncthreads();
    for (int i = tid; i < N; i += 1024)
        atomicAdd(&lh[cell_of(x[3 * i], x[3 * i + 1], x[3 * i + 2])], 1);
    __syncthreads();
    if (tid < NCELL) {                     // first wave: shfl inclusive scan
        int v = lh[tid], incl = v;
        for (int o = 1; o < NCELL; o <<= 1) {
            int t = __shfl_up(incl, o);
            if (tid >= o) incl += t;
        }
        offs[tid + 1] = incl;
        if (tid == 0) offs[0] = 0;
        lcur[tid] = incl - v;              // exclusive prefix = global cursor
    }
    __syncthreads();
    for (int i = tid; i < N; i += 1024) {
        float a = x[3 * i], b = x[3 * i + 1], c = x[3 * i + 2];
        int pos = atomicAdd(&lcur[cell_of(a, b, c)], 1);
        xs[pos] = a; ys[pos] = b; zs[pos] = c; perm[pos] = i;
    }
}

// ---------------- main sparse kernel ----------------
template <int SET>  // 0: ux,uy,uz   1: P,Px   2: Q,Qy   3: R,Rz
__device__ __forceinline__ void srbf_cell_body(
    const float* __restrict__ xs, const float* __restrict__ ys,
    const float* __restrict__ zs,
    const float* __restrict__ h, const float* __restrict__ c,
    const float* __restrict__ w,
    const int* __restrict__ offs, const int* __restrict__ perm,
    float* __restrict__ dst, int N, int jbase, int jcount, int direct,
    float4* lds4)
{
    constexpr int OB = (SET == 0) ? 0 : (2 * SET + 1);
    const int tid = threadIdx.x, lane = tid & 63, wv = tid >> 6;  // 128 thr
    float* ldsb2 = (float*)(lds4 + 2 * jcount);
    int*   slist = (int*)(ldsb2 + jcount);
    int*   pcnt  = slist + jcount;

    // stage per-center constants
    for (int jj = tid; jj < jcount; jj += 128) {
        const int gj = jbase + jj;
        float hj  = h[gj];
        float w0  = w[3 * gj + 0] * SQRT_LOG2E;
        float w1  = w[3 * gj + 1] * SQRT_LOG2E;
        float w2  = w[3 * gj + 2] * SQRT_LOG2E;
        float cw0 = -c[3 * gj + 0] * w0;
        float cw1 = -c[3 * gj + 1] * w1;
        float cw2 = -c[3 * gj + 2] * w2;
        lds4[jj * 2 + 0] = make_float4(w0, w1, w2, cw0);
        if constexpr (SET == 0) {
            lds4[jj * 2 + 1] = make_float4(cw1, cw2, NEG_2LN2 * hj * w0,
                                           NEG_2LN2 * hj * w1);
            ldsb2[jj] = NEG_2LN2 * hj * w2;
        } else {
            constexpr int K = SET - 1;
            float wk = (K == 0) ? w0 : (K == 1 ? w1 : w2);
            lds4[jj * 2 + 1] = make_float4(cw1, cw2, hj, NEG_2LN2 * hj * wk);
        }
    }
    __syncthreads();

    // fixed cell box -> survivor list, built by wave 0 (deterministic order)
    const int cellid = blockIdx.x;
    const float mid0 = ((cellid & 3) + 0.5f) * 0.25f;
    const float mid1 = (((cellid >> 2) & 3) + 0.5f) * 0.25f;
    const float mid2 = (((cellid >> 4) & 3) + 0.5f) * 0.25f;
    const float hf = 0.125f;
    if (wv == 0) {
        int cnt = 0;
        for (int j0 = 0; j0 < jcount; j0 += 64) {
            const float4 A = lds4[(j0 + lane) * 2 + 0];
            const float4 B = lds4[(j0 + lane) * 2 + 1];
            float v0  = fmaf(mid0, A.x, A.w);
            float v1  = fmaf(mid1, A.y, B.x);
            float v2_ = fmaf(mid2, A.z, B.y);
            float d0 = fmaxf(fabsf(v0)  - hf * A.x, 0.f);
            float d1 = fmaxf(fabsf(v1)  - hf * A.y, 0.f);
            float d2 = fmaxf(fabsf(v2_) - hf * A.z, 0.f);
            float smin = fmaf(d0, d0, fmaf(d1, d1, d2 * d2));
            bool surv = smin < S2_CUT;
            unsigned long long m = __ballot(surv);
            int pos = cnt + __popcll(m & ((1ull << lane) - 1ull));
            if (surv) slist[pos] = j0 + lane;
            cnt += __popcll(m);
        }
        if (lane == 0) *pcnt = cnt;
    }
    __syncthreads();
    const int cnt = *pcnt;
    const int start = offs[cellid], end = offs[cellid + 1];

    for (int base = start + 256 * wv; base < end; base += 512) {
        int i0 = base + lane;
        int idx[4]; bool val[4];
#pragma unroll
        for (int g4 = 0; g4 < 4; ++g4) {
            int q = i0 + 64 * g4;
            val[g4] = (q < end);
            idx[g4] = val[g4] ? q : (end - 1);
        }
        v2f px[2], py[2], pz[2];
        px[0] = (v2f){xs[idx[0]], xs[idx[1]]};
        py[0] = (v2f){ys[idx[0]], ys[idx[1]]};
        pz[0] = (v2f){zs[idx[0]], zs[idx[1]]};
        px[1] = (v2f){xs[idx[2]], xs[idx[3]]};
        py[1] = (v2f){ys[idx[2]], ys[idx[3]]};
        pz[1] = (v2f){zs[idx[2]], zs[idx[3]]};

        v2f a0[2] = {sp(0.f), sp(0.f)};
        v2f a1[2] = {sp(0.f), sp(0.f)};
        v2f a2[2] = {sp(0.f), sp(0.f)};

#pragma unroll 2
        for (int si = 0; si < cnt; ++si) {
            const int jj = slist[si];
            const float4 A = lds4[jj * 2 + 0];   // w0,w1,w2,cw0
            const float4 B = lds4[jj * 2 + 1];   // cw1,cw2,(b0|h),(b1|bk)
            float b2 = 0.f;
            if constexpr (SET == 0) b2 = ldsb2[jj];
#pragma unroll
            for (int g = 0; g < 2; ++g) {
                v2f t0 = vfma(px[g], sp(A.x), sp(A.w));
                v2f t1 = vfma(py[g], sp(A.y), sp(B.x));
                v2f t2 = vfma(pz[g], sp(A.z), sp(B.y));
                v2f s  = vfma(t0, t0, vfma(t1, t1, t2 * t2));
                v2f e  = (v2f){__builtin_amdgcn_exp2f(-s.x),
                               __builtin_amdgcn_exp2f(-s.y)};
                if constexpr (SET == 0) {
                    a0[g] = vfma(t0, sp(B.z) * e, a0[g]);
                    a1[g] = vfma(t1, sp(B.w) * e, a1[g]);
                    a2[g] = vfma(t2, sp(b2)  * e, a2[g]);
                } else {
                    constexpr int K = SET - 1;
                    v2f tk = (K == 0) ? t0 : (K == 1 ? t1 : t2);
                    a0[g] = vfma(sp(B.z), e, a0[g]);
                    a1[g] = vfma(tk, sp(B.w) * e, a1[g]);
                }
            }
        }

        float r0[4] = {a0[0].x, a0[0].y, a0[1].x, a0[1].y};
        float r1[4] = {a1[0].x, a1[0].y, a1[1].x, a1[1].y};
        float r2[4] = {a2[0].x, a2[0].y, a2[1].x, a2[1].y};
#pragma unroll
        for (int g4 = 0; g4 < 4; ++g4) {
            if (!val[g4]) continue;
            int pos = i0 + 64 * g4;
            int tgt = direct ? perm[pos] : pos;
            dst[(OB + 0) * N + tgt] = r0[g4];
            dst[(OB + 1) * N + tgt] = r1[g4];
            if constexpr (SET == 0) dst[2 * N + tgt] = r2[g4];
        }
    }
}

__global__ __launch_bounds__(128, 8) void srbf_sorted(
    const float* xs, const float* ys, const float* zs,
    const float* h1, const float* c1, const float* w1,
    const float* h2, const float* c2, const float* w2,
    const float* h3, const float* c3, const float* w3,
    const float* h4, const float* c4, const float* w4,
    const int* offs, const int* perm,
    float* out, float* ws, int N, int jcount, int split)
{
    extern __shared__ float4 lds4[];
    const int jbase = blockIdx.y * jcount;
    const int direct = (split == 1);
    float* dst = direct ? out : (ws + (size_t)blockIdx.y * 9 * N);
    switch (blockIdx.z) {
    case 0: srbf_cell_body<0>(xs, ys, zs, h1, c1, w1, offs, perm, dst, N, jbase, jcount, direct, lds4); break;
    case 1: srbf_cell_body<1>(xs, ys, zs, h2, c2, w2, offs, perm, dst, N, jbase, jcount, direct, lds4); break;
    case 2: srbf_cell_body<2>(xs, ys, zs, h3, c3, w3, offs, perm, dst, N, jbase, jcount, direct, lds4); break;
    case 3: srbf_cell_body<3>(xs, ys, zs, h4, c4, w4, offs, perm, dst, N, jbase, jcount, direct, lds4); break;
    }
}

__global__ __launch_bounds__(256) void reduce_scatter(
    const float* __restrict__ ws, const int* __restrict__ perm,
    float* __restrict__ out, int N, int split)
{
    int pos = blockIdx.x * 256 + threadIdx.x;
    if (pos < N) {
        int op = perm[pos];
#pragma unroll
        for (int row = 0; row < 9; ++row) {
            float acc = 0.f;
            for (int p = 0; p < split; ++p)
                acc += ws[((size_t)p * 9 + row) * N + pos];
            out[row * N + op] = acc;
        }
    }
}

// ---------------- R4 dense fallback ----------------
template <int SET>
__device__ __forceinline__ void srbf_body_fb(
    const float* __restrict__ x, const float* __restrict__ h,
    const float* __restrict__ c, const float* __restrict__ w,
    float* __restrict__ dst, int N, int jbase, int jcount, float4* lds4)
{
    constexpr int OB = (SET == 0) ? 0 : (2 * SET + 1);
    const int tid = threadIdx.x;
    float* ldsb2 = (float*)(lds4 + 2 * jcount);
    for (int jj = tid; jj < jcount; jj += 256) {
        const int gj = jbase + jj;
        float hj  = h[gj];
        float w0  = w[3 * gj + 0] * SQRT_LOG2E;
        float w1  = w[3 * gj + 1] * SQRT_LOG2E;
        float w2  = w[3 * gj + 2] * SQRT_LOG2E;
        float cw0 = -c[3 * gj + 0] * w0;
        float cw1 = -c[3 * gj + 1] * w1;
        float cw2 = -c[3 * gj + 2] * w2;
        lds4[jj * 2 + 0] = make_float4(w0, w1, w2, cw0);
        if constexpr (SET == 0) {
            lds4[jj * 2 + 1] = make_float4(cw1, cw2, NEG_2LN2 * hj * w0, NEG_2LN2 * hj * w1);
            ldsb2[jj] = NEG_2LN2 * hj * w2;
        } else {
            constexpr int K = SET - 1;
            float wk = (K == 0) ? w0 : (K == 1 ? w1 : w2);
            lds4[jj * 2 + 1] = make_float4(cw1, cw2, hj, NEG_2LN2 * hj * wk);
        }
    }
    __syncthreads();
    const int i0 = blockIdx.x * 1024 + tid;
    v2f px[2], py[2], pz[2];
#pragma unroll
    for (int g = 0; g < 2; ++g) {
        const int ia = i0 + 512 * g, ib = ia + 256;
        px[g] = (v2f){x[3 * ia + 0], x[3 * ib + 0]};
        py[g] = (v2f){x[3 * ia + 1], x[3 * ib + 1]};
        pz[g] = (v2f){x[3 * ia + 2], x[3 * ib + 2]};
    }
    v2f a0[2] = {sp(0.f), sp(0.f)}, a1[2] = {sp(0.f), sp(0.f)}, a2[2] = {sp(0.f), sp(0.f)};
#pragma unroll 2
    for (int jj = 0; jj < jcount; ++jj) {
        const float4 A = lds4[jj * 2 + 0];
        const float4 B = lds4[jj * 2 + 1];
        float b2 = 0.f;
        if constexpr (SET == 0) b2 = ldsb2[jj];
#pragma unroll
        for (int g = 0; g < 2; ++g) {
            v2f t0 = vfma(px[g], sp(A.x), sp(A.w));
            v2f t1 = vfma(py[g], sp(A.y), sp(B.x));
            v2f t2 = vfma(pz[g], sp(A.z), sp(B.y));
            v2f s  = vfma(t0, t0, vfma(t1, t1, t2 * t2));
            v2f e  = (v2f){__builtin_amdgcn_exp2f(-s.x), __builtin_amdgcn_exp2f(-s.y)};
            if constexpr (SET == 0) {
                a0[g] = vfma(t0, sp(B.z) * e, a0[g]);
                a1[g] = vfma(t1, sp(B.w) * e, a1[g]);
                a2[g] = vfma(t2, sp(b2)  * e, a2[g]);
            } else {
                constexpr int K = SET - 1;
                v2f tk = (K == 0) ? t0 : (K == 1 ? t1 : t2);
                a0[g] = vfma(sp(B.z), e, a0[g]);
                a1[g] = vfma(tk, sp(B.w) * e, a1[g]);
            }
        }
    }
#pragma unroll
    for (int g = 0; g < 2; ++g) {
        const int ia = i0 + 512 * g, ib = ia + 256;
        dst[(OB + 0) * N + ia] = a0[g].x;  dst[(OB + 0) * N + ib] = a0[g].y;
        dst[(OB + 1) * N + ia] = a1[g].x;  dst[(OB + 1) * N + ib] = a1[g].y;
        if constexpr (SET == 0) { dst[2 * N + ia] = a2[g].x; dst[2 * N + ib] = a2[g].y; }
    }
}

__global__ __launch_bounds__(256, 8) void srbf_fallback(
    const float* x,
    const float* h1, const float* c1, const float* w1,
    const float* h2, const float* c2, const float* w2,
    const float* h3, const float* c3, const float* w3,
    const float* h4, const float* c4, const float* w4,
    float* out, float* ws, int N, int jcount, int split)
{
    extern __shared__ float4 lds4[];
    const int jbase = blockIdx.y * jcount;
    float* dst = (split > 1) ? (ws + (size_t)blockIdx.y * 9 * N) : out;
    switch (blockIdx.z) {
    case 0: srbf_body_fb<0>(x, h1, c1, w1, dst, N, jbase, jcount, lds4); break;
    case 1: srbf_body_fb<1>(x, h2, c2, w2, dst, N, jbase, jcount, lds4); break;
    case 2: srbf_body_fb<2>(x, h3, c3, w3, dst, N, jbase, jcount, lds4); break;
    case 3: srbf_body_fb<3>(x, h4, c4, w4, dst, N, jbase, jcount, lds4); break;
    }
}

__global__ __launch_bounds__(256) void reduce_fb(
    const float4* __restrict__ ws, float4* __restrict__ out, int total4, int split)
{
    const int i = blockIdx.x * 256 + threadIdx.x;
    if (i < total4) {
        float4 acc = ws[i];
#pragma unroll 16
        for (int p = 1; p < split; ++p) {
            const float4 v = ws[(size_t)p * total4 + i];
            acc.x += v.x; acc.y += v.y; acc.z += v.z; acc.w += v.w;
        }
        out[i] = acc;
    }
}

// ---------------- launch ----------------
extern "C" void kernel_launch(void* const* d_in, const int* in_sizes, int n_in,
                              void* d_out, int out_size, void* d_ws, size_t ws_size,
                              hipStream_t stream)
{
    const float* x = (const float*)d_in[0];
    const int N  = in_sizes[0] / 3;   // 32768
    const int N1 = in_sizes[1];       // 1024
    float* out = (float*)d_out;
    float* wsf = (float*)d_ws;

    // ws floats: partials split*9N | xs N | ys N | zs N | perm N | offs 65
    int split = 0;
    {
        const int cand[4] = {8, 4, 2, 1};
        for (int ci = 0; ci < 4; ++ci) {
            int s = cand[ci];
            if ((N1 % s) == 0 &&
                ws_size >= ((size_t)s * 9 * N + 4 * (size_t)N + 80) * 4) {
                split = s; break;
            }
        }
    }

    if (split) {
        size_t off = (size_t)split * 9 * N;
        float* xs = wsf + off;
        float* ys = xs + N;
        float* zs = ys + N;
        int* perm = (int*)(zs + N);
        int* offs = perm + N;

        sort_kernel<<<1, 1024, 0, stream>>>(x, xs, ys, zs, perm, offs, N);

        const int jcount = N1 / split;
        dim3 grid(NCELL, split, 4);
        const size_t lds_bytes = (size_t)jcount * 40 + 16;
        srbf_sorted<<<grid, 128, lds_bytes, stream>>>(
            xs, ys, zs,
            (const float*)d_in[1],  (const float*)d_in[2],  (const float*)d_in[3],
            (const float*)d_in[4],  (const float*)d_in[5],  (const float*)d_in[6],
            (const float*)d_in[7],  (const float*)d_in[8],  (const float*)d_in[9],
            (const float*)d_in[10], (const float*)d_in[11], (const float*)d_in[12],
            offs, perm, out, wsf, N, jcount, split);

        if (split > 1)
            reduce_scatter<<<(N + 255) / 256, 256, 0, stream>>>(wsf, perm, out, N, split);
    } else {
        int fsplit = 1;
        for (int s = 16; s >= 2; s >>= 1) {
            if (ws_size >= (size_t)s * 9 * N * sizeof(float) && (N1 % s) == 0) {
                fsplit = s; break;
            }
        }
        const int jcount = N1 / fsplit;
        dim3 grid(N / 1024, fsplit, 4);
        const size_t lds_bytes = (size_t)jcount * (2 * sizeof(float4) + sizeof(float));
        srbf_fallback<<<grid, 256, lds_bytes, stream>>>(
            x,
            (const float*)d_in[1],  (const float*)d_in[2],  (const float*)d_in[3],
            (const float*)d_in[4],  (const float*)d_in[5],  (const float*)d_in[6],
            (const float*)d_in[7],  (const float*)d_in[8],  (const float*)d_in[9],
            (const float*)d_in[10], (const float*)d_in[11], (const float*)d_in[12],
            out, wsf, N, jcount, fsplit);
        if (fsplit > 1) {
            const int total4 = 9 * N / 4;
            reduce_fb<<<(total4 + 255) / 256, 256, 0, stream>>>(
                (const float4*)wsf, (float4*)out, total4, fsplit);
        }
    }
}

// Round 8
// 63.562 us; speedup vs baseline: 2.7052x; 1.6434x over previous
//
#include <hip/hip_runtime.h>

// e = exp(-((x-cx)^2 w0^2 + ...)) with w' = w*sqrt(log2 e):
//   t_k = fma(x_k, w'_k, -c_k w'_k);  e = exp2(-(t0^2+t1^2+t2^2))
// du_k = -2 x1_k w_k^2 h e = t_k * (NEG_2LN2 * h * w'_k) * e
//
// R7: fully parallel two-level counting sort (LDS hist + per-block range
// reservation), iperm gather-reduce (coalesced out writes), S2_CUT=22.
// Output values are independent of intra-cell point order => deterministic.
typedef float v2f __attribute__((ext_vector_type(2)));

static constexpr float SQRT_LOG2E = 1.2011224087864498f;   // sqrt(log2(e))
static constexpr float NEG_2LN2   = -1.3862943611198906f;  // -2*ln(2)
static constexpr float S2_CUT     = 22.0f;                 // drop if smin >= 22 (log2 units)
#define NCELL 64                                           // 4x4x4

__device__ __forceinline__ v2f sp(float s) { return (v2f){s, s}; }
__device__ __forceinline__ v2f vfma(v2f a, v2f b, v2f c) {
    return __builtin_elementwise_fma(a, b, c);
}

__device__ __forceinline__ int cell_of(float a, float b, float c) {
    int cx = (int)(a * 4.f); cx = cx < 0 ? 0 : (cx > 3 ? 3 : cx);
    int cy = (int)(b * 4.f); cy = cy < 0 ? 0 : (cy > 3 ? 3 : cy);
    int cz = (int)(c * 4.f); cz = cz < 0 ? 0 : (cz > 3 ? 3 : cz);
    return cx + 4 * cy + 16 * cz;
}

// ---------------- parallel counting sort ----------------
__global__ __launch_bounds__(256) void hist_kernel(
    const float* __restrict__ x, int* __restrict__ hist, int N)
{
    __shared__ int lh[NCELL];
    const int tid = threadIdx.x;
    if (tid < NCELL) lh[tid] = 0;
    __syncthreads();
    int i = blockIdx.x * 256 + tid;
    if (i < N) atomicAdd(&lh[cell_of(x[3 * i], x[3 * i + 1], x[3 * i + 2])], 1);
    __syncthreads();
    if (tid < NCELL && lh[tid]) atomicAdd(&hist[tid], lh[tid]);
}

__global__ __launch_bounds__(256) void scatter_kernel(
    const float* __restrict__ x, const int* __restrict__ hist, int* __restrict__ gcur,
    float* __restrict__ xs, float* __restrict__ ys, float* __restrict__ zs,
    int* __restrict__ iperm, int N)
{
    __shared__ int sexcl[NCELL], lcnt[NCELL], lbase[NCELL];
    const int tid = threadIdx.x;
    if (tid < 64) {                       // wave 0: global exclusive scan
        int hv = hist[tid], incl = hv;
        for (int o = 1; o < 64; o <<= 1) {
            int t = __shfl_up(incl, o);
            if (tid >= o) incl += t;
        }
        sexcl[tid] = incl - hv;
    } else if (tid < 128) {
        lcnt[tid - 64] = 0;
    }
    __syncthreads();
    const int i = blockIdx.x * 256 + tid;
    int cell = 0, r = 0; float a = 0.f, b = 0.f, c = 0.f;
    const bool ok = i < N;
    if (ok) {
        a = x[3 * i]; b = x[3 * i + 1]; c = x[3 * i + 2];
        cell = cell_of(a, b, c);
        r = atomicAdd(&lcnt[cell], 1);
    }
    __syncthreads();
    if (tid < 64) lbase[tid] = lcnt[tid] ? atomicAdd(&gcur[tid], lcnt[tid]) : 0;
    __syncthreads();
    if (ok) {
        int pos = sexcl[cell] + lbase[cell] + r;
        xs[pos] = a; ys[pos] = b; zs[pos] = c; iperm[i] = pos;
    }
}

// ---------------- main sparse kernel ----------------
template <int SET>  // 0: ux,uy,uz   1: P,Px   2: Q,Qy   3: R,Rz
__device__ __forceinline__ void srbf_cell_body(
    const float* __restrict__ xs, const float* __restrict__ ys,
    const float* __restrict__ zs,
    const float* __restrict__ h, const float* __restrict__ c,
    const float* __restrict__ w, const int* __restrict__ hist,
    float* __restrict__ dst, int N, int jbase, int jcount, float4* lds4)
{
    constexpr int OB = (SET == 0) ? 0 : (2 * SET + 1);
    const int tid = threadIdx.x, lane = tid & 63, wv = tid >> 6;  // 128 thr
    float* ldsb2 = (float*)(lds4 + 2 * jcount);
    int*   slist = (int*)(ldsb2 + jcount);
    int*   sexcl = slist + jcount;
    int*   scnt  = sexcl + NCELL;
    int*   pcnt  = scnt + NCELL;

    // stage per-center constants
    for (int jj = tid; jj < jcount; jj += 128) {
        const int gj = jbase + jj;
        float hj  = h[gj];
        float w0  = w[3 * gj + 0] * SQRT_LOG2E;
        float w1  = w[3 * gj + 1] * SQRT_LOG2E;
        float w2  = w[3 * gj + 2] * SQRT_LOG2E;
        float cw0 = -c[3 * gj + 0] * w0;
        float cw1 = -c[3 * gj + 1] * w1;
        float cw2 = -c[3 * gj + 2] * w2;
        lds4[jj * 2 + 0] = make_float4(w0, w1, w2, cw0);
        if constexpr (SET == 0) {
            lds4[jj * 2 + 1] = make_float4(cw1, cw2, NEG_2LN2 * hj * w0,
                                           NEG_2LN2 * hj * w1);
            ldsb2[jj] = NEG_2LN2 * hj * w2;
        } else {
            constexpr int K = SET - 1;
            float wk = (K == 0) ? w0 : (K == 1 ? w1 : w2);
            lds4[jj * 2 + 1] = make_float4(cw1, cw2, hj, NEG_2LN2 * hj * wk);
        }
    }
    __syncthreads();

    const int cellid = blockIdx.x;
    const float mid0 = ((cellid & 3) + 0.5f) * 0.25f;
    const float mid1 = (((cellid >> 2) & 3) + 0.5f) * 0.25f;
    const float mid2 = (((cellid >> 4) & 3) + 0.5f) * 0.25f;
    const float hf = 0.125f;

    if (wv == 0) {
        // global offset scan (64-wide, wave 0)
        int hv = hist[lane], incl = hv;
        for (int o = 1; o < 64; o <<= 1) {
            int t = __shfl_up(incl, o);
            if (lane >= o) incl += t;
        }
        sexcl[lane] = incl - hv;
        scnt[lane]  = hv;
        // survivor list vs fixed cell box (deterministic ascending order)
        int cnt = 0;
        for (int j0 = 0; j0 < jcount; j0 += 64) {
            const float4 A = lds4[(j0 + lane) * 2 + 0];
            const float4 B = lds4[(j0 + lane) * 2 + 1];
            float v0  = fmaf(mid0, A.x, A.w);
            float v1  = fmaf(mid1, A.y, B.x);
            float v2_ = fmaf(mid2, A.z, B.y);
            float d0 = fmaxf(fabsf(v0)  - hf * A.x, 0.f);
            float d1 = fmaxf(fabsf(v1)  - hf * A.y, 0.f);
            float d2 = fmaxf(fabsf(v2_) - hf * A.z, 0.f);
            float smin = fmaf(d0, d0, fmaf(d1, d1, d2 * d2));
            bool surv = smin < S2_CUT;
            unsigned long long m = __ballot(surv);
            int pos = cnt + __popcll(m & ((1ull << lane) - 1ull));
            if (surv) slist[pos] = j0 + lane;
            cnt += __popcll(m);
        }
        if (lane == 0) *pcnt = cnt;
    }
    __syncthreads();
    const int cnt = *pcnt;
    const int start = sexcl[cellid], end = start + scnt[cellid];

    for (int base = start + 256 * wv; base < end; base += 512) {
        int i0 = base + lane;
        int idx[4]; bool val[4];
#pragma unroll
        for (int g4 = 0; g4 < 4; ++g4) {
            int q = i0 + 64 * g4;
            val[g4] = (q < end);
            idx[g4] = val[g4] ? q : (end - 1);
        }
        v2f px[2], py[2], pz[2];
        px[0] = (v2f){xs[idx[0]], xs[idx[1]]};
        py[0] = (v2f){ys[idx[0]], ys[idx[1]]};
        pz[0] = (v2f){zs[idx[0]], zs[idx[1]]};
        px[1] = (v2f){xs[idx[2]], xs[idx[3]]};
        py[1] = (v2f){ys[idx[2]], ys[idx[3]]};
        pz[1] = (v2f){zs[idx[2]], zs[idx[3]]};

        v2f a0[2] = {sp(0.f), sp(0.f)};
        v2f a1[2] = {sp(0.f), sp(0.f)};
        v2f a2[2] = {sp(0.f), sp(0.f)};

#pragma unroll 2
        for (int si = 0; si < cnt; ++si) {
            const int jj = slist[si];
            const float4 A = lds4[jj * 2 + 0];   // w0,w1,w2,cw0
            const float4 B = lds4[jj * 2 + 1];   // cw1,cw2,(b0|h),(b1|bk)
            float b2 = 0.f;
            if constexpr (SET == 0) b2 = ldsb2[jj];
#pragma unroll
            for (int g = 0; g < 2; ++g) {
                v2f t0 = vfma(px[g], sp(A.x), sp(A.w));
                v2f t1 = vfma(py[g], sp(A.y), sp(B.x));
                v2f t2 = vfma(pz[g], sp(A.z), sp(B.y));
                v2f s  = vfma(t0, t0, vfma(t1, t1, t2 * t2));
                v2f e  = (v2f){__builtin_amdgcn_exp2f(-s.x),
                               __builtin_amdgcn_exp2f(-s.y)};
                if constexpr (SET == 0) {
                    a0[g] = vfma(t0, sp(B.z) * e, a0[g]);
                    a1[g] = vfma(t1, sp(B.w) * e, a1[g]);
                    a2[g] = vfma(t2, sp(b2)  * e, a2[g]);
                } else {
                    constexpr int K = SET - 1;
                    v2f tk = (K == 0) ? t0 : (K == 1 ? t1 : t2);
                    a0[g] = vfma(sp(B.z), e, a0[g]);
                    a1[g] = vfma(tk, sp(B.w) * e, a1[g]);
                }
            }
        }

        float r0[4] = {a0[0].x, a0[0].y, a0[1].x, a0[1].y};
        float r1[4] = {a1[0].x, a1[0].y, a1[1].x, a1[1].y};
        float r2[4] = {a2[0].x, a2[0].y, a2[1].x, a2[1].y};
#pragma unroll
        for (int g4 = 0; g4 < 4; ++g4) {
            if (!val[g4]) continue;
            int pos = i0 + 64 * g4;
            dst[(OB + 0) * N + pos] = r0[g4];
            dst[(OB + 1) * N + pos] = r1[g4];
            if constexpr (SET == 0) dst[2 * N + pos] = r2[g4];
        }
    }
}

__global__ __launch_bounds__(128, 8) void srbf_sorted(
    const float* xs, const float* ys, const float* zs,
    const float* h1, const float* c1, const float* w1,
    const float* h2, const float* c2, const float* w2,
    const float* h3, const float* c3, const float* w3,
    const float* h4, const float* c4, const float* w4,
    const int* hist, float* ws, int N, int jcount)
{
    extern __shared__ float4 lds4[];
    const int jbase = blockIdx.y * jcount;
    float* dst = ws + (size_t)blockIdx.y * 9 * N;
    switch (blockIdx.z) {
    case 0: srbf_cell_body<0>(xs, ys, zs, h1, c1, w1, hist, dst, N, jbase, jcount, lds4); break;
    case 1: srbf_cell_body<1>(xs, ys, zs, h2, c2, w2, hist, dst, N, jbase, jcount, lds4); break;
    case 2: srbf_cell_body<2>(xs, ys, zs, h3, c3, w3, hist, dst, N, jbase, jcount, lds4); break;
    case 3: srbf_cell_body<3>(xs, ys, zs, h4, c4, w4, hist, dst, N, jbase, jcount, lds4); break;
    }
}

__global__ __launch_bounds__(256) void reduce_gather(
    const float* __restrict__ ws, const int* __restrict__ iperm,
    float* __restrict__ out, int N, int split)
{
    const int i = blockIdx.x * 256 + threadIdx.x;   // original index: coalesced writes
    if (i < N) {
        const int pos = iperm[i];
#pragma unroll
        for (int row = 0; row < 9; ++row) {
            float acc = 0.f;
            for (int p = 0; p < split; ++p)
                acc += ws[((size_t)p * 9 + row) * N + pos];
            out[row * N + i] = acc;
        }
    }
}

// ---------------- R4 dense fallback ----------------
template <int SET>
__device__ __forceinline__ void srbf_body_fb(
    const float* __restrict__ x, const float* __restrict__ h,
    const float* __restrict__ c, const float* __restrict__ w,
    float* __restrict__ dst, int N, int jbase, int jcount, float4* lds4)
{
    constexpr int OB = (SET == 0) ? 0 : (2 * SET + 1);
    const int tid = threadIdx.x;
    float* ldsb2 = (float*)(lds4 + 2 * jcount);
    for (int jj = tid; jj < jcount; jj += 256) {
        const int gj = jbase + jj;
        float hj  = h[gj];
        float w0  = w[3 * gj + 0] * SQRT_LOG2E;
        float w1  = w[3 * gj + 1] * SQRT_LOG2E;
        float w2  = w[3 * gj + 2] * SQRT_LOG2E;
        float cw0 = -c[3 * gj + 0] * w0;
        float cw1 = -c[3 * gj + 1] * w1;
        float cw2 = -c[3 * gj + 2] * w2;
        lds4[jj * 2 + 0] = make_float4(w0, w1, w2, cw0);
        if constexpr (SET == 0) {
            lds4[jj * 2 + 1] = make_float4(cw1, cw2, NEG_2LN2 * hj * w0, NEG_2LN2 * hj * w1);
            ldsb2[jj] = NEG_2LN2 * hj * w2;
        } else {
            constexpr int K = SET - 1;
            float wk = (K == 0) ? w0 : (K == 1 ? w1 : w2);
            lds4[jj * 2 + 1] = make_float4(cw1, cw2, hj, NEG_2LN2 * hj * wk);
        }
    }
    __syncthreads();
    const int i0 = blockIdx.x * 1024 + tid;
    v2f px[2], py[2], pz[2];
#pragma unroll
    for (int g = 0; g < 2; ++g) {
        const int ia = i0 + 512 * g, ib = ia + 256;
        px[g] = (v2f){x[3 * ia + 0], x[3 * ib + 0]};
        py[g] = (v2f){x[3 * ia + 1], x[3 * ib + 1]};
        pz[g] = (v2f){x[3 * ia + 2], x[3 * ib + 2]};
    }
    v2f a0[2] = {sp(0.f), sp(0.f)}, a1[2] = {sp(0.f), sp(0.f)}, a2[2] = {sp(0.f), sp(0.f)};
#pragma unroll 2
    for (int jj = 0; jj < jcount; ++jj) {
        const float4 A = lds4[jj * 2 + 0];
        const float4 B = lds4[jj * 2 + 1];
        float b2 = 0.f;
        if constexpr (SET == 0) b2 = ldsb2[jj];
#pragma unroll
        for (int g = 0; g < 2; ++g) {
            v2f t0 = vfma(px[g], sp(A.x), sp(A.w));
            v2f t1 = vfma(py[g], sp(A.y), sp(B.x));
            v2f t2 = vfma(pz[g], sp(A.z), sp(B.y));
            v2f s  = vfma(t0, t0, vfma(t1, t1, t2 * t2));
            v2f e  = (v2f){__builtin_amdgcn_exp2f(-s.x), __builtin_amdgcn_exp2f(-s.y)};
            if constexpr (SET == 0) {
                a0[g] = vfma(t0, sp(B.z) * e, a0[g]);
                a1[g] = vfma(t1, sp(B.w) * e, a1[g]);
                a2[g] = vfma(t2, sp(b2)  * e, a2[g]);
            } else {
                constexpr int K = SET - 1;
                v2f tk = (K == 0) ? t0 : (K == 1 ? t1 : t2);
                a0[g] = vfma(sp(B.z), e, a0[g]);
                a1[g] = vfma(tk, sp(B.w) * e, a1[g]);
            }
        }
    }
#pragma unroll
    for (int g = 0; g < 2; ++g) {
        const int ia = i0 + 512 * g, ib = ia + 256;
        dst[(OB + 0) * N + ia] = a0[g].x;  dst[(OB + 0) * N + ib] = a0[g].y;
        dst[(OB + 1) * N + ia] = a1[g].x;  dst[(OB + 1) * N + ib] = a1[g].y;
        if constexpr (SET == 0) { dst[2 * N + ia] = a2[g].x; dst[2 * N + ib] = a2[g].y; }
    }
}

__global__ __launch_bounds__(256, 8) void srbf_fallback(
    const float* x,
    const float* h1, const float* c1, const float* w1,
    const float* h2, const float* c2, const float* w2,
    const float* h3, const float* c3, const float* w3,
    const float* h4, const float* c4, const float* w4,
    float* out, float* ws, int N, int jcount, int split)
{
    extern __shared__ float4 lds4[];
    const int jbase = blockIdx.y * jcount;
    float* dst = (split > 1) ? (ws + (size_t)blockIdx.y * 9 * N) : out;
    switch (blockIdx.z) {
    case 0: srbf_body_fb<0>(x, h1, c1, w1, dst, N, jbase, jcount, lds4); break;
    case 1: srbf_body_fb<1>(x, h2, c2, w2, dst, N, jbase, jcount, lds4); break;
    case 2: srbf_body_fb<2>(x, h3, c3, w3, dst, N, jbase, jcount, lds4); break;
    case 3: srbf_body_fb<3>(x, h4, c4, w4, dst, N, jbase, jcount, lds4); break;
    }
}

__global__ __launch_bounds__(256) void reduce_fb(
    const float4* __restrict__ ws, float4* __restrict__ out, int total4, int split)
{
    const int i = blockIdx.x * 256 + threadIdx.x;
    if (i < total4) {
        float4 acc = ws[i];
#pragma unroll 16
        for (int p = 1; p < split; ++p) {
            const float4 v = ws[(size_t)p * total4 + i];
            acc.x += v.x; acc.y += v.y; acc.z += v.z; acc.w += v.w;
        }
        out[i] = acc;
    }
}

// ---------------- launch ----------------
extern "C" void kernel_launch(void* const* d_in, const int* in_sizes, int n_in,
                              void* d_out, int out_size, void* d_ws, size_t ws_size,
                              hipStream_t stream)
{
    const float* x = (const float*)d_in[0];
    const int N  = in_sizes[0] / 3;   // 32768
    const int N1 = in_sizes[1];       // 1024
    float* out = (float*)d_out;
    float* wsf = (float*)d_ws;

    // ws floats: partials split*9N | xs N | ys N | zs N | iperm N | hist 64 | gcur 64
    int split = 0;
    {
        const int cand[3] = {8, 4, 2};
        for (int ci = 0; ci < 3; ++ci) {
            int s = cand[ci];
            if ((N1 % s) == 0 &&
                ws_size >= ((size_t)s * 9 * N + 4 * (size_t)N + 128) * 4) {
                split = s; break;
            }
        }
    }

    if (split) {
        size_t off = (size_t)split * 9 * N;
        float* xs  = wsf + off;
        float* ys  = xs + N;
        float* zs  = ys + N;
        int* iperm = (int*)(zs + N);
        int* hist  = iperm + N;
        int* gcur  = hist + NCELL;

        hipMemsetAsync(hist, 0, 2 * NCELL * sizeof(int), stream);
        const int nb = (N + 255) / 256;
        hist_kernel<<<nb, 256, 0, stream>>>(x, hist, N);
        scatter_kernel<<<nb, 256, 0, stream>>>(x, hist, gcur, xs, ys, zs, iperm, N);

        const int jcount = N1 / split;
        dim3 grid(NCELL, split, 4);
        const size_t lds_bytes = (size_t)jcount * 40 + NCELL * 8 + 16;
        srbf_sorted<<<grid, 128, lds_bytes, stream>>>(
            xs, ys, zs,
            (const float*)d_in[1],  (const float*)d_in[2],  (const float*)d_in[3],
            (const float*)d_in[4],  (const float*)d_in[5],  (const float*)d_in[6],
            (const float*)d_in[7],  (const float*)d_in[8],  (const float*)d_in[9],
            (const float*)d_in[10], (const float*)d_in[11], (const float*)d_in[12],
            hist, wsf, N, jcount);

        reduce_gather<<<nb, 256, 0, stream>>>(wsf, iperm, out, N, split);
    } else {
        int fsplit = 1;
        for (int s = 16; s >= 2; s >>= 1) {
            if (ws_size >= (size_t)s * 9 * N * sizeof(float) && (N1 % s) == 0) {
                fsplit = s; break;
            }
        }
        const int jcount = N1 / fsplit;
        dim3 grid(N / 1024, fsplit, 4);
        const size_t lds_bytes = (size_t)jcount * (2 * sizeof(float4) + sizeof(float));
        srbf_fallback<<<grid, 256, lds_bytes, stream>>>(
            x,
            (const float*)d_in[1],  (const float*)d_in[2],  (const float*)d_in[3],
            (const float*)d_in[4],  (const float*)d_in[5],  (const float*)d_in[6],
            (const float*)d_in[7],  (const float*)d_in[8],  (const float*)d_in[9],
            (const float*)d_in[10], (const float*)d_in[11], (const float*)d_in[12],
            out, wsf, N, jcount, fsplit);
        if (fsplit > 1) {
            const int total4 = 9 * N / 4;
            reduce_fb<<<(total4 + 255) / 256, 256, 0, stream>>>(
                (const float4*)wsf, (float4*)out, total4, fsplit);
        }
    }
}

// Round 9
// 62.767 us; speedup vs baseline: 2.7394x; 1.0127x over previous
//
#include <hip/hip_runtime.h>

// e = exp(-((x-cx)^2 w0^2 + ...)) with w' = w*sqrt(log2 e):
//   t_k = fma(x_k, w'_k, -c_k w'_k);  e = exp2(-(t0^2+t1^2+t2^2))
// du_k = -2 x1_k w_k^2 h e = t_k * (NEG_2LN2 * h * w'_k) * e
//
// R8: identical to R7 except the 512-byte hipMemsetAsync (rocclr fillBuffer
// = 45us/replay in graph, measured) is replaced by a 1-block zero kernel.
typedef float v2f __attribute__((ext_vector_type(2)));

static constexpr float SQRT_LOG2E = 1.2011224087864498f;   // sqrt(log2(e))
static constexpr float NEG_2LN2   = -1.3862943611198906f;  // -2*ln(2)
static constexpr float S2_CUT     = 22.0f;                 // drop if smin >= 22 (log2 units)
#define NCELL 64                                           // 4x4x4

__device__ __forceinline__ v2f sp(float s) { return (v2f){s, s}; }
__device__ __forceinline__ v2f vfma(v2f a, v2f b, v2f c) {
    return __builtin_elementwise_fma(a, b, c);
}

__device__ __forceinline__ int cell_of(float a, float b, float c) {
    int cx = (int)(a * 4.f); cx = cx < 0 ? 0 : (cx > 3 ? 3 : cx);
    int cy = (int)(b * 4.f); cy = cy < 0 ? 0 : (cy > 3 ? 3 : cy);
    int cz = (int)(c * 4.f); cz = cz < 0 ? 0 : (cz > 3 ? 3 : cz);
    return cx + 4 * cy + 16 * cz;
}

// ---------------- tiny zero (replaces pathological hipMemsetAsync) --------
__global__ __launch_bounds__(128) void zero_kernel(int* __restrict__ p) {
    p[threadIdx.x] = 0;    // hist[64] + gcur[64], contiguous
}

// ---------------- parallel counting sort ----------------
__global__ __launch_bounds__(256) void hist_kernel(
    const float* __restrict__ x, int* __restrict__ hist, int N)
{
    __shared__ int lh[NCELL];
    const int tid = threadIdx.x;
    if (tid < NCELL) lh[tid] = 0;
    __syncthreads();
    int i = blockIdx.x * 256 + tid;
    if (i < N) atomicAdd(&lh[cell_of(x[3 * i], x[3 * i + 1], x[3 * i + 2])], 1);
    __syncthreads();
    if (tid < NCELL && lh[tid]) atomicAdd(&hist[tid], lh[tid]);
}

__global__ __launch_bounds__(256) void scatter_kernel(
    const float* __restrict__ x, const int* __restrict__ hist, int* __restrict__ gcur,
    float* __restrict__ xs, float* __restrict__ ys, float* __restrict__ zs,
    int* __restrict__ iperm, int N)
{
    __shared__ int sexcl[NCELL], lcnt[NCELL], lbase[NCELL];
    const int tid = threadIdx.x;
    if (tid < 64) {                       // wave 0: global exclusive scan
        int hv = hist[tid], incl = hv;
        for (int o = 1; o < 64; o <<= 1) {
            int t = __shfl_up(incl, o);
            if (tid >= o) incl += t;
        }
        sexcl[tid] = incl - hv;
    } else if (tid < 128) {
        lcnt[tid - 64] = 0;
    }
    __syncthreads();
    const int i = blockIdx.x * 256 + tid;
    int cell = 0, r = 0; float a = 0.f, b = 0.f, c = 0.f;
    const bool ok = i < N;
    if (ok) {
        a = x[3 * i]; b = x[3 * i + 1]; c = x[3 * i + 2];
        cell = cell_of(a, b, c);
        r = atomicAdd(&lcnt[cell], 1);
    }
    __syncthreads();
    if (tid < 64) lbase[tid] = lcnt[tid] ? atomicAdd(&gcur[tid], lcnt[tid]) : 0;
    __syncthreads();
    if (ok) {
        int pos = sexcl[cell] + lbase[cell] + r;
        xs[pos] = a; ys[pos] = b; zs[pos] = c; iperm[i] = pos;
    }
}

// ---------------- main sparse kernel ----------------
template <int SET>  // 0: ux,uy,uz   1: P,Px   2: Q,Qy   3: R,Rz
__device__ __forceinline__ void srbf_cell_body(
    const float* __restrict__ xs, const float* __restrict__ ys,
    const float* __restrict__ zs,
    const float* __restrict__ h, const float* __restrict__ c,
    const float* __restrict__ w, const int* __restrict__ hist,
    float* __restrict__ dst, int N, int jbase, int jcount, float4* lds4)
{
    constexpr int OB = (SET == 0) ? 0 : (2 * SET + 1);
    const int tid = threadIdx.x, lane = tid & 63, wv = tid >> 6;  // 128 thr
    float* ldsb2 = (float*)(lds4 + 2 * jcount);
    int*   slist = (int*)(ldsb2 + jcount);
    int*   sexcl = slist + jcount;
    int*   scnt  = sexcl + NCELL;
    int*   pcnt  = scnt + NCELL;

    // stage per-center constants
    for (int jj = tid; jj < jcount; jj += 128) {
        const int gj = jbase + jj;
        float hj  = h[gj];
        float w0  = w[3 * gj + 0] * SQRT_LOG2E;
        float w1  = w[3 * gj + 1] * SQRT_LOG2E;
        float w2  = w[3 * gj + 2] * SQRT_LOG2E;
        float cw0 = -c[3 * gj + 0] * w0;
        float cw1 = -c[3 * gj + 1] * w1;
        float cw2 = -c[3 * gj + 2] * w2;
        lds4[jj * 2 + 0] = make_float4(w0, w1, w2, cw0);
        if constexpr (SET == 0) {
            lds4[jj * 2 + 1] = make_float4(cw1, cw2, NEG_2LN2 * hj * w0,
                                           NEG_2LN2 * hj * w1);
            ldsb2[jj] = NEG_2LN2 * hj * w2;
        } else {
            constexpr int K = SET - 1;
            float wk = (K == 0) ? w0 : (K == 1 ? w1 : w2);
            lds4[jj * 2 + 1] = make_float4(cw1, cw2, hj, NEG_2LN2 * hj * wk);
        }
    }
    __syncthreads();

    const int cellid = blockIdx.x;
    const float mid0 = ((cellid & 3) + 0.5f) * 0.25f;
    const float mid1 = (((cellid >> 2) & 3) + 0.5f) * 0.25f;
    const float mid2 = (((cellid >> 4) & 3) + 0.5f) * 0.25f;
    const float hf = 0.125f;

    if (wv == 0) {
        // global offset scan (64-wide, wave 0)
        int hv = hist[lane], incl = hv;
        for (int o = 1; o < 64; o <<= 1) {
            int t = __shfl_up(incl, o);
            if (lane >= o) incl += t;
        }
        sexcl[lane] = incl - hv;
        scnt[lane]  = hv;
        // survivor list vs fixed cell box (deterministic ascending order)
        int cnt = 0;
        for (int j0 = 0; j0 < jcount; j0 += 64) {
            const float4 A = lds4[(j0 + lane) * 2 + 0];
            const float4 B = lds4[(j0 + lane) * 2 + 1];
            float v0  = fmaf(mid0, A.x, A.w);
            float v1  = fmaf(mid1, A.y, B.x);
            float v2_ = fmaf(mid2, A.z, B.y);
            float d0 = fmaxf(fabsf(v0)  - hf * A.x, 0.f);
            float d1 = fmaxf(fabsf(v1)  - hf * A.y, 0.f);
            float d2 = fmaxf(fabsf(v2_) - hf * A.z, 0.f);
            float smin = fmaf(d0, d0, fmaf(d1, d1, d2 * d2));
            bool surv = smin < S2_CUT;
            unsigned long long m = __ballot(surv);
            int pos = cnt + __popcll(m & ((1ull << lane) - 1ull));
            if (surv) slist[pos] = j0 + lane;
            cnt += __popcll(m);
        }
        if (lane == 0) *pcnt = cnt;
    }
    __syncthreads();
    const int cnt = *pcnt;
    const int start = sexcl[cellid], end = start + scnt[cellid];

    for (int base = start + 256 * wv; base < end; base += 512) {
        int i0 = base + lane;
        int idx[4]; bool val[4];
#pragma unroll
        for (int g4 = 0; g4 < 4; ++g4) {
            int q = i0 + 64 * g4;
            val[g4] = (q < end);
            idx[g4] = val[g4] ? q : (end - 1);
        }
        v2f px[2], py[2], pz[2];
        px[0] = (v2f){xs[idx[0]], xs[idx[1]]};
        py[0] = (v2f){ys[idx[0]], ys[idx[1]]};
        pz[0] = (v2f){zs[idx[0]], zs[idx[1]]};
        px[1] = (v2f){xs[idx[2]], xs[idx[3]]};
        py[1] = (v2f){ys[idx[2]], ys[idx[3]]};
        pz[1] = (v2f){zs[idx[2]], zs[idx[3]]};

        v2f a0[2] = {sp(0.f), sp(0.f)};
        v2f a1[2] = {sp(0.f), sp(0.f)};
        v2f a2[2] = {sp(0.f), sp(0.f)};

#pragma unroll 2
        for (int si = 0; si < cnt; ++si) {
            const int jj = slist[si];
            const float4 A = lds4[jj * 2 + 0];   // w0,w1,w2,cw0
            const float4 B = lds4[jj * 2 + 1];   // cw1,cw2,(b0|h),(b1|bk)
            float b2 = 0.f;
            if constexpr (SET == 0) b2 = ldsb2[jj];
#pragma unroll
            for (int g = 0; g < 2; ++g) {
                v2f t0 = vfma(px[g], sp(A.x), sp(A.w));
                v2f t1 = vfma(py[g], sp(A.y), sp(B.x));
                v2f t2 = vfma(pz[g], sp(A.z), sp(B.y));
                v2f s  = vfma(t0, t0, vfma(t1, t1, t2 * t2));
                v2f e  = (v2f){__builtin_amdgcn_exp2f(-s.x),
                               __builtin_amdgcn_exp2f(-s.y)};
                if constexpr (SET == 0) {
                    a0[g] = vfma(t0, sp(B.z) * e, a0[g]);
                    a1[g] = vfma(t1, sp(B.w) * e, a1[g]);
                    a2[g] = vfma(t2, sp(b2)  * e, a2[g]);
                } else {
                    constexpr int K = SET - 1;
                    v2f tk = (K == 0) ? t0 : (K == 1 ? t1 : t2);
                    a0[g] = vfma(sp(B.z), e, a0[g]);
                    a1[g] = vfma(tk, sp(B.w) * e, a1[g]);
                }
            }
        }

        float r0[4] = {a0[0].x, a0[0].y, a0[1].x, a0[1].y};
        float r1[4] = {a1[0].x, a1[0].y, a1[1].x, a1[1].y};
        float r2[4] = {a2[0].x, a2[0].y, a2[1].x, a2[1].y};
#pragma unroll
        for (int g4 = 0; g4 < 4; ++g4) {
            if (!val[g4]) continue;
            int pos = i0 + 64 * g4;
            dst[(OB + 0) * N + pos] = r0[g4];
            dst[(OB + 1) * N + pos] = r1[g4];
            if constexpr (SET == 0) dst[2 * N + pos] = r2[g4];
        }
    }
}

__global__ __launch_bounds__(128, 8) void srbf_sorted(
    const float* xs, const float* ys, const float* zs,
    const float* h1, const float* c1, const float* w1,
    const float* h2, const float* c2, const float* w2,
    const float* h3, const float* c3, const float* w3,
    const float* h4, const float* c4, const float* w4,
    const int* hist, float* ws, int N, int jcount)
{
    extern __shared__ float4 lds4[];
    const int jbase = blockIdx.y * jcount;
    float* dst = ws + (size_t)blockIdx.y * 9 * N;
    switch (blockIdx.z) {
    case 0: srbf_cell_body<0>(xs, ys, zs, h1, c1, w1, hist, dst, N, jbase, jcount, lds4); break;
    case 1: srbf_cell_body<1>(xs, ys, zs, h2, c2, w2, hist, dst, N, jbase, jcount, lds4); break;
    case 2: srbf_cell_body<2>(xs, ys, zs, h3, c3, w3, hist, dst, N, jbase, jcount, lds4); break;
    case 3: srbf_cell_body<3>(xs, ys, zs, h4, c4, w4, hist, dst, N, jbase, jcount, lds4); break;
    }
}

__global__ __launch_bounds__(256) void reduce_gather(
    const float* __restrict__ ws, const int* __restrict__ iperm,
    float* __restrict__ out, int N, int split)
{
    const int i = blockIdx.x * 256 + threadIdx.x;   // original index: coalesced writes
    if (i < N) {
        const int pos = iperm[i];
#pragma unroll
        for (int row = 0; row < 9; ++row) {
            float acc = 0.f;
            for (int p = 0; p < split; ++p)
                acc += ws[((size_t)p * 9 + row) * N + pos];
            out[row * N + i] = acc;
        }
    }
}

// ---------------- R4 dense fallback ----------------
template <int SET>
__device__ __forceinline__ void srbf_body_fb(
    const float* __restrict__ x, const float* __restrict__ h,
    const float* __restrict__ c, const float* __restrict__ w,
    float* __restrict__ dst, int N, int jbase, int jcount, float4* lds4)
{
    constexpr int OB = (SET == 0) ? 0 : (2 * SET + 1);
    const int tid = threadIdx.x;
    float* ldsb2 = (float*)(lds4 + 2 * jcount);
    for (int jj = tid; jj < jcount; jj += 256) {
        const int gj = jbase + jj;
        float hj  = h[gj];
        float w0  = w[3 * gj + 0] * SQRT_LOG2E;
        float w1  = w[3 * gj + 1] * SQRT_LOG2E;
        float w2  = w[3 * gj + 2] * SQRT_LOG2E;
        float cw0 = -c[3 * gj + 0] * w0;
        float cw1 = -c[3 * gj + 1] * w1;
        float cw2 = -c[3 * gj + 2] * w2;
        lds4[jj * 2 + 0] = make_float4(w0, w1, w2, cw0);
        if constexpr (SET == 0) {
            lds4[jj * 2 + 1] = make_float4(cw1, cw2, NEG_2LN2 * hj * w0, NEG_2LN2 * hj * w1);
            ldsb2[jj] = NEG_2LN2 * hj * w2;
        } else {
            constexpr int K = SET - 1;
            float wk = (K == 0) ? w0 : (K == 1 ? w1 : w2);
            lds4[jj * 2 + 1] = make_float4(cw1, cw2, hj, NEG_2LN2 * hj * wk);
        }
    }
    __syncthreads();
    const int i0 = blockIdx.x * 1024 + tid;
    v2f px[2], py[2], pz[2];
#pragma unroll
    for (int g = 0; g < 2; ++g) {
        const int ia = i0 + 512 * g, ib = ia + 256;
        px[g] = (v2f){x[3 * ia + 0], x[3 * ib + 0]};
        py[g] = (v2f){x[3 * ia + 1], x[3 * ib + 1]};
        pz[g] = (v2f){x[3 * ia + 2], x[3 * ib + 2]};
    }
    v2f a0[2] = {sp(0.f), sp(0.f)}, a1[2] = {sp(0.f), sp(0.f)}, a2[2] = {sp(0.f), sp(0.f)};
#pragma unroll 2
    for (int jj = 0; jj < jcount; ++jj) {
        const float4 A = lds4[jj * 2 + 0];
        const float4 B = lds4[jj * 2 + 1];
        float b2 = 0.f;
        if constexpr (SET == 0) b2 = ldsb2[jj];
#pragma unroll
        for (int g = 0; g < 2; ++g) {
            v2f t0 = vfma(px[g], sp(A.x), sp(A.w));
            v2f t1 = vfma(py[g], sp(A.y), sp(B.x));
            v2f t2 = vfma(pz[g], sp(A.z), sp(B.y));
            v2f s  = vfma(t0, t0, vfma(t1, t1, t2 * t2));
            v2f e  = (v2f){__builtin_amdgcn_exp2f(-s.x), __builtin_amdgcn_exp2f(-s.y)};
            if constexpr (SET == 0) {
                a0[g] = vfma(t0, sp(B.z) * e, a0[g]);
                a1[g] = vfma(t1, sp(B.w) * e, a1[g]);
                a2[g] = vfma(t2, sp(b2)  * e, a2[g]);
            } else {
                constexpr int K = SET - 1;
                v2f tk = (K == 0) ? t0 : (K == 1 ? t1 : t2);
                a0[g] = vfma(sp(B.z), e, a0[g]);
                a1[g] = vfma(tk, sp(B.w) * e, a1[g]);
            }
        }
    }
#pragma unroll
    for (int g = 0; g < 2; ++g) {
        const int ia = i0 + 512 * g, ib = ia + 256;
        dst[(OB + 0) * N + ia] = a0[g].x;  dst[(OB + 0) * N + ib] = a0[g].y;
        dst[(OB + 1) * N + ia] = a1[g].x;  dst[(OB + 1) * N + ib] = a1[g].y;
        if constexpr (SET == 0) { dst[2 * N + ia] = a2[g].x; dst[2 * N + ib] = a2[g].y; }
    }
}

__global__ __launch_bounds__(256, 8) void srbf_fallback(
    const float* x,
    const float* h1, const float* c1, const float* w1,
    const float* h2, const float* c2, const float* w2,
    const float* h3, const float* c3, const float* w3,
    const float* h4, const float* c4, const float* w4,
    float* out, float* ws, int N, int jcount, int split)
{
    extern __shared__ float4 lds4[];
    const int jbase = blockIdx.y * jcount;
    float* dst = (split > 1) ? (ws + (size_t)blockIdx.y * 9 * N) : out;
    switch (blockIdx.z) {
    case 0: srbf_body_fb<0>(x, h1, c1, w1, dst, N, jbase, jcount, lds4); break;
    case 1: srbf_body_fb<1>(x, h2, c2, w2, dst, N, jbase, jcount, lds4); break;
    case 2: srbf_body_fb<2>(x, h3, c3, w3, dst, N, jbase, jcount, lds4); break;
    case 3: srbf_body_fb<3>(x, h4, c4, w4, dst, N, jbase, jcount, lds4); break;
    }
}

__global__ __launch_bounds__(256) void reduce_fb(
    const float4* __restrict__ ws, float4* __restrict__ out, int total4, int split)
{
    const int i = blockIdx.x * 256 + threadIdx.x;
    if (i < total4) {
        float4 acc = ws[i];
#pragma unroll 16
        for (int p = 1; p < split; ++p) {
            const float4 v = ws[(size_t)p * total4 + i];
            acc.x += v.x; acc.y += v.y; acc.z += v.z; acc.w += v.w;
        }
        out[i] = acc;
    }
}

// ---------------- launch ----------------
extern "C" void kernel_launch(void* const* d_in, const int* in_sizes, int n_in,
                              void* d_out, int out_size, void* d_ws, size_t ws_size,
                              hipStream_t stream)
{
    const float* x = (const float*)d_in[0];
    const int N  = in_sizes[0] / 3;   // 32768
    const int N1 = in_sizes[1];       // 1024
    float* out = (float*)d_out;
    float* wsf = (float*)d_ws;

    // ws floats: partials split*9N | xs N | ys N | zs N | iperm N | hist 64 | gcur 64
    int split = 0;
    {
        const int cand[3] = {8, 4, 2};
        for (int ci = 0; ci < 3; ++ci) {
            int s = cand[ci];
            if ((N1 % s) == 0 &&
                ws_size >= ((size_t)s * 9 * N + 4 * (size_t)N + 128) * 4) {
                split = s; break;
            }
        }
    }

    if (split) {
        size_t off = (size_t)split * 9 * N;
        float* xs  = wsf + off;
        float* ys  = xs + N;
        float* zs  = ys + N;
        int* iperm = (int*)(zs + N);
        int* hist  = iperm + N;
        // gcur = hist + 64 (zeroed together by zero_kernel)

        zero_kernel<<<1, 128, 0, stream>>>(hist);
        const int nb = (N + 255) / 256;
        hist_kernel<<<nb, 256, 0, stream>>>(x, hist, N);
        scatter_kernel<<<nb, 256, 0, stream>>>(x, hist, hist + NCELL, xs, ys, zs, iperm, N);

        const int jcount = N1 / split;
        dim3 grid(NCELL, split, 4);
        const size_t lds_bytes = (size_t)jcount * 40 + NCELL * 8 + 16;
        srbf_sorted<<<grid, 128, lds_bytes, stream>>>(
            xs, ys, zs,
            (const float*)d_in[1],  (const float*)d_in[2],  (const float*)d_in[3],
            (const float*)d_in[4],  (const float*)d_in[5],  (const float*)d_in[6],
            (const float*)d_in[7],  (const float*)d_in[8],  (const float*)d_in[9],
            (const float*)d_in[10], (const float*)d_in[11], (const float*)d_in[12],
            hist, wsf, N, jcount);

        reduce_gather<<<nb, 256, 0, stream>>>(wsf, iperm, out, N, split);
    } else {
        int fsplit = 1;
        for (int s = 16; s >= 2; s >>= 1) {
            if (ws_size >= (size_t)s * 9 * N * sizeof(float) && (N1 % s) == 0) {
                fsplit = s; break;
            }
        }
        const int jcount = N1 / fsplit;
        dim3 grid(N / 1024, fsplit, 4);
        const size_t lds_bytes = (size_t)jcount * (2 * sizeof(float4) + sizeof(float));
        srbf_fallback<<<grid, 256, lds_bytes, stream>>>(
            x,
            (const float*)d_in[1],  (const float*)d_in[2],  (const float*)d_in[3],
            (const float*)d_in[4],  (const float*)d_in[5],  (const float*)d_in[6],
            (const float*)d_in[7],  (const float*)d_in[8],  (const float*)d_in[9],
            (const float*)d_in[10], (const float*)d_in[11], (const float*)d_in[12],
            out, wsf, N, jcount, fsplit);
        if (fsplit > 1) {
            const int total4 = 9 * N / 4;
            reduce_fb<<<(total4 + 255) / 256, 256, 0, stream>>>(
                (const float4*)wsf, (float4*)out, total4, fsplit);
        }
    }
}